// Round 1
// baseline (653.567 us; speedup 1.0000x reference)
//
#include <hip/hip_runtime.h>

// ---------------------------------------------------------------------------
// Fused multimodal net: l-MLP + 2 LSTMs (MFMA bf16) + tiny transformer head.
// N=4096 samples, T=256 steps, DA=74, DV=47, hidden=32 (128 gate rows).
// ---------------------------------------------------------------------------

typedef float float4v __attribute__((ext_vector_type(4)));
typedef short short4v __attribute__((ext_vector_type(4)));

#define N_SAMPLES 4096
#define T_STEPS 256

__device__ __forceinline__ short bf16r(float f) {
  // round-to-nearest-even f32 -> bf16 bits
  unsigned u = __float_as_uint(f);
  u += 0x7FFFu + ((u >> 16) & 1u);
  return (short)(u >> 16);
}

__device__ __forceinline__ float sigmoidf_(float v) {
  return __fdividef(1.0f, 1.0f + __expf(-v));
}
__device__ __forceinline__ float tanhf_fast(float v) {
  // tanh(x) = 1 - 2/(exp(2x)+1); graceful at +-inf
  return 1.0f - __fdividef(2.0f, __expf(2.0f * v) + 1.0f);
}

__device__ __forceinline__ float4v mfma16(short4v a, short4v b, float4v c) {
  return __builtin_amdgcn_mfma_f32_16x16x16bf16_1k(a, b, c, 0, 0, 0);
}

// ---------------------------------------------------------------------------
// LSTM: one wave owns 16 samples end-to-end. gates[128 x 16] = Wih@x + Whh@h
// via MFMA tiles (8 gate-tiles x (NKX + 2) k-tiles). Bias folded into the
// d==D pad column (x element = 1.0). C-layout of h == B-frag layout, so the
// recurrence is register-only (pack f32->bf16 per lane).
// gate rows: [0:32)=i, [32:64)=f, [64:96)=g, [96:128)=o  (PyTorch order)
// ---------------------------------------------------------------------------
template <int D, int NKX>
__device__ void lstm_core(const float* __restrict__ x,
                          const float* __restrict__ Wih,
                          const float* __restrict__ Whh,
                          const float* __restrict__ bih,
                          const float* __restrict__ bhh,
                          const float* __restrict__ Wo,
                          const float* __restrict__ bo,
                          float* __restrict__ outf, int n0) {
  const int lane = threadIdx.x;      // 0..63
  const int colc = lane & 15;        // sample within wave (N-col of MFMA)
  const int q    = lane >> 4;        // k-quad
  const int n    = n0 + colc;
  constexpr int NKT = NKX + 2;       // + two 16-wide h k-tiles

  // ---- stationary weight A-fragments (row = gate row = lane&15 slice) ----
  short4v wf[8][NKT];
#pragma unroll
  for (int gt = 0; gt < 8; ++gt) {
    const int row = gt * 16 + colc;
    const float bsum = bih[row] + bhh[row];
    const float* wr = Wih + row * D;
#pragma unroll
    for (int kt = 0; kt < NKX; ++kt) {
      short4v s;
#pragma unroll
      for (int e = 0; e < 4; ++e) {
        const int d = kt * 16 + q * 4 + e;
        float val = 0.0f;
        if (d < D) val = wr[d];
        else if (d == D) val = bsum;   // bias column
        s[e] = bf16r(val);
      }
      wf[gt][kt] = s;
    }
    const float* hr = Whh + row * 32;
#pragma unroll
    for (int ht = 0; ht < 2; ++ht) {
      short4v s;
#pragma unroll
      for (int e = 0; e < 4; ++e) s[e] = bf16r(hr[ht * 16 + q * 4 + e]);
      wf[gt][NKX + ht] = s;
    }
  }

  // ---- state ----
  float c_st[2][4];
  short4v hB[2];
#pragma unroll
  for (int i = 0; i < 4; ++i) {
    c_st[0][i] = 0.0f; c_st[1][i] = 0.0f;
    hB[0][i] = 0; hB[1][i] = 0;
  }

  const float* xp = x + (size_t)n * D;
  const size_t tstride = (size_t)N_SAMPLES * D;

  // prefetch x for t=0
  float xf[NKX][4];
#pragma unroll
  for (int kt = 0; kt < NKX; ++kt)
#pragma unroll
    for (int e = 0; e < 4; ++e) {
      const int d = kt * 16 + q * 4 + e;
      float val = 0.0f;
      if (d < D) val = xp[d];
      else if (d == D) val = 1.0f;
      xf[kt][e] = val;
    }

  for (int t = 0; t < T_STEPS; ++t) {
    // convert current x to B-fragments
    short4v xB[NKX];
#pragma unroll
    for (int kt = 0; kt < NKX; ++kt) {
      short4v s;
#pragma unroll
      for (int e = 0; e < 4; ++e) s[e] = bf16r(xf[kt][e]);
      xB[kt] = s;
    }
    // prefetch x for t+1 (overlaps MFMA + nonlinearity)
    if (t + 1 < T_STEPS) {
      const float* xn = xp + tstride;
#pragma unroll
      for (int kt = 0; kt < NKX; ++kt)
#pragma unroll
        for (int e = 0; e < 4; ++e) {
          const int d = kt * 16 + q * 4 + e;
          float val = 0.0f;
          if (d < D) val = xn[d];
          else if (d == D) val = 1.0f;
          xf[kt][e] = val;
        }
    }
    xp += tstride;

    // gates = Wih@x + Whh@h (+ folded biases)
    float4v acc[8];
#pragma unroll
    for (int gt = 0; gt < 8; ++gt) {
      float4v a4 = {0.0f, 0.0f, 0.0f, 0.0f};
#pragma unroll
      for (int kt = 0; kt < NKX; ++kt) a4 = mfma16(wf[gt][kt], xB[kt], a4);
      a4 = mfma16(wf[gt][NKX], hB[0], a4);
      a4 = mfma16(wf[gt][NKX + 1], hB[1], a4);
      acc[gt] = a4;
    }

    // elementwise state update in C-layout; repack h as next B-frag
#pragma unroll
    for (int tau = 0; tau < 2; ++tau) {
#pragma unroll
      for (int r = 0; r < 4; ++r) {
        const float iv = sigmoidf_(acc[tau][r]);
        const float fv = sigmoidf_(acc[2 + tau][r]);
        const float gv = tanhf_fast(acc[4 + tau][r]);
        const float ov = sigmoidf_(acc[6 + tau][r]);
        const float cv = fv * c_st[tau][r] + iv * gv;
        c_st[tau][r] = cv;
        hB[tau][r] = bf16r(ov * tanhf_fast(cv));
      }
    }
  }

  // out = relu(hT @ Wo^T + bo)  via 2 more MFMAs (K=32)
#pragma unroll
  for (int ot = 0; ot < 2; ++ot) {
    const int row = ot * 16 + colc;
    const float* wor = Wo + row * 32;
    short4v w0, w1;
#pragma unroll
    for (int e = 0; e < 4; ++e) {
      w0[e] = bf16r(wor[q * 4 + e]);
      w1[e] = bf16r(wor[16 + q * 4 + e]);
    }
    float4v o4 = {0.0f, 0.0f, 0.0f, 0.0f};
    o4 = mfma16(w0, hB[0], o4);
    o4 = mfma16(w1, hB[1], o4);
#pragma unroll
    for (int r = 0; r < 4; ++r) {
      const int u = ot * 16 + q * 4 + r;
      outf[(size_t)n * 32 + u] = fmaxf(o4[r] + bo[u], 0.0f);
    }
  }
}

__global__ __launch_bounds__(64, 2) void lstm_both(
    const float* __restrict__ a, const float* __restrict__ v,
    const float* __restrict__ aWih, const float* __restrict__ aWhh,
    const float* __restrict__ abih, const float* __restrict__ abhh,
    const float* __restrict__ aWo, const float* __restrict__ abo,
    const float* __restrict__ vWih, const float* __restrict__ vWhh,
    const float* __restrict__ vbih, const float* __restrict__ vbhh,
    const float* __restrict__ vWo, const float* __restrict__ vbo,
    float* __restrict__ afw, float* __restrict__ vfw) {
  const int b = blockIdx.x;
  if (b < 256)
    lstm_core<74, 5>(a, aWih, aWhh, abih, abhh, aWo, abo, afw, b * 16);
  else
    lstm_core<47, 3>(v, vWih, vWhh, vbih, vbhh, vWo, vbo, vfw, (b - 256) * 16);
}

// ---------------------------------------------------------------------------
// lf = relu(relu(l @ lW1^T + lb1) @ lW2^T + lb2)   [4096,768]->[4096,32]
// block = 256 threads, 16 samples; l tile staged in LDS (48 KB), fp32 exact.
// ---------------------------------------------------------------------------
__global__ __launch_bounds__(256) void lf_kernel(
    const float* __restrict__ l, const float* __restrict__ lW1,
    const float* __restrict__ lb1, const float* __restrict__ lW2,
    const float* __restrict__ lb2, float* __restrict__ lf) {
  __shared__ __align__(16) float lsh[16 * 768];
  __shared__ __align__(16) float h1sh[16 * 128];
  const int tid = threadIdx.x;
  const int n0 = blockIdx.x * 16;

  {
    const float4v* src = (const float4v*)(l + (size_t)n0 * 768);
    float4v* dst = (float4v*)lsh;
#pragma unroll
    for (int i = 0; i < 12; ++i) dst[tid + i * 256] = src[tid + i * 256];
  }
  __syncthreads();

  {  // phase 1: h1[16][128]
    const int u = tid & 127;
    const int sg = tid >> 7;  // 0/1 -> samples sg*8..sg*8+7
    float acc[8];
#pragma unroll
    for (int i = 0; i < 8; ++i) acc[i] = 0.0f;
    const float4v* wrow = (const float4v*)(lW1 + u * 768);
    for (int k4 = 0; k4 < 192; ++k4) {
      const float4v w = wrow[k4];
#pragma unroll
      for (int i = 0; i < 8; ++i) {
        const float4v xv = ((const float4v*)(lsh + (sg * 8 + i) * 768))[k4];
        acc[i] += w[0] * xv[0] + w[1] * xv[1] + w[2] * xv[2] + w[3] * xv[3];
      }
    }
    const float b = lb1[u];
#pragma unroll
    for (int i = 0; i < 8; ++i)
      h1sh[(sg * 8 + i) * 128 + u] = fmaxf(acc[i] + b, 0.0f);
  }
  __syncthreads();

  {  // phase 2: lf[16][32]
    const int u2 = tid & 31;
    const int sg2 = tid >> 5;  // 0..7 -> samples sg2, sg2+8
    float acc0 = 0.0f, acc1 = 0.0f;
    const float4v* w2 = (const float4v*)(lW2 + u2 * 128);
#pragma unroll
    for (int k4 = 0; k4 < 32; ++k4) {
      const float4v w = w2[k4];
      const float4v xa = ((const float4v*)(h1sh + sg2 * 128))[k4];
      const float4v xb = ((const float4v*)(h1sh + (sg2 + 8) * 128))[k4];
      acc0 += w[0] * xa[0] + w[1] * xa[1] + w[2] * xa[2] + w[3] * xa[3];
      acc1 += w[0] * xb[0] + w[1] * xb[1] + w[2] * xb[2] + w[3] * xb[3];
    }
    const float b2 = lb2[u2];
    lf[(size_t)(n0 + sg2) * 32 + u2] = fmaxf(acc0 + b2, 0.0f);
    lf[(size_t)(n0 + sg2 + 8) * 32 + u2] = fmaxf(acc1 + b2, 0.0f);
  }
}

// ---------------------------------------------------------------------------
// Transformer block + post-fusion head. 32 lanes per sample (lane = feature
// j = h*8+e), 8 samples per 256-thread block. All reductions via shfl.
// ---------------------------------------------------------------------------
__global__ __launch_bounds__(256) void head_kernel(
    const float* __restrict__ lf, const float* __restrict__ af,
    const float* __restrict__ vf, const float* __restrict__ Wq,
    const float* __restrict__ bq, const float* __restrict__ Wk,
    const float* __restrict__ bk, const float* __restrict__ Wv,
    const float* __restrict__ bv, const float* __restrict__ Wz,
    const float* __restrict__ bz, const float* __restrict__ Wff,
    const float* __restrict__ bff, const float* __restrict__ g1,
    const float* __restrict__ be1, const float* __restrict__ g2,
    const float* __restrict__ be2, const float* __restrict__ Wp1,
    const float* __restrict__ bp1, const float* __restrict__ Wp2,
    const float* __restrict__ bp2, float* __restrict__ out) {
  __shared__ float shA[8][3][33];
  __shared__ float shB[8][3][33];
  const int tid = threadIdx.x;
  const int j = tid & 31;
  const int slot = tid >> 5;  // 0..7
  const int n = blockIdx.x * 8 + slot;
  const size_t off = (size_t)n * 32 + j;

  const float x0 = lf[off], x1 = af[off], x2 = vf[off];

  // joint LayerNorm over (3,32) with affine g/be
  auto ln3 = [&](float a0, float a1, float a2, const float* g,
                 const float* be, float* o) {
    float s = a0 + a1 + a2;
    s += __shfl_xor(s, 1); s += __shfl_xor(s, 2); s += __shfl_xor(s, 4);
    s += __shfl_xor(s, 8); s += __shfl_xor(s, 16);
    const float mu = s * (1.0f / 96.0f);
    const float d0 = a0 - mu, d1 = a1 - mu, d2 = a2 - mu;
    float ss = d0 * d0 + d1 * d1 + d2 * d2;
    ss += __shfl_xor(ss, 1); ss += __shfl_xor(ss, 2); ss += __shfl_xor(ss, 4);
    ss += __shfl_xor(ss, 8); ss += __shfl_xor(ss, 16);
    const float rs = rsqrtf(ss * (1.0f / 96.0f) + 1e-5f);
    o[0] = d0 * rs * g[j] + be[j];
    o[1] = d1 * rs * g[32 + j] + be[32 + j];
    o[2] = d2 * rs * g[64 + j] + be[64 + j];
  };

  float z[3];
  ln3(x0, x1, x2, g1, be1, z);
  shA[slot][0][j] = z[0]; shA[slot][1][j] = z[1]; shA[slot][2][j] = z[2];
  __syncthreads();  // #1

  // Q/K/V for this lane's (head h=j>>3, unit e=j&7)
  float qv[3], kv[3], vv[3];
  {
    const float bqj = bq[j], bkj = bk[j], bvj = bv[j];
    qv[0] = bqj; qv[1] = bqj; qv[2] = bqj;
    kv[0] = bkj; kv[1] = bkj; kv[2] = bkj;
    vv[0] = bvj; vv[1] = bvj; vv[2] = bvj;
    const float* wqr = Wq + j * 32;
    const float* wkr = Wk + j * 32;
    const float* wvr = Wv + j * 32;
#pragma unroll 8
    for (int k = 0; k < 32; ++k) {
      const float zz0 = shA[slot][0][k], zz1 = shA[slot][1][k],
                  zz2 = shA[slot][2][k];
      const float wq = wqr[k], wk_ = wkr[k], wv_ = wvr[k];
      qv[0] += wq * zz0;  qv[1] += wq * zz1;  qv[2] += wq * zz2;
      kv[0] += wk_ * zz0; kv[1] += wk_ * zz1; kv[2] += wk_ * zz2;
      vv[0] += wv_ * zz0; vv[1] += wv_ * zz1; vv[2] += wv_ * zz2;
    }
  }

  // scores (octet reduce over e), softmax over t FIRST, then / sqrt(8)
  float at[3][3];
#pragma unroll
  for (int s = 0; s < 3; ++s)
#pragma unroll
    for (int t2 = 0; t2 < 3; ++t2) {
      float p = qv[s] * kv[t2];
      p += __shfl_xor(p, 1); p += __shfl_xor(p, 2); p += __shfl_xor(p, 4);
      at[s][t2] = p;
    }
#pragma unroll
  for (int s = 0; s < 3; ++s) {
    const float m = fmaxf(fmaxf(at[s][0], at[s][1]), at[s][2]);
    const float e0 = __expf(at[s][0] - m), e1 = __expf(at[s][1] - m),
                e2 = __expf(at[s][2] - m);
    const float sc = 0.35355339059327373f * __fdividef(1.0f, e0 + e1 + e2);
    at[s][0] = e0 * sc; at[s][1] = e1 * sc; at[s][2] = e2 * sc;
  }
  float zc[3];
#pragma unroll
  for (int s = 0; s < 3; ++s)
    zc[s] = at[s][0] * vv[0] + at[s][1] * vv[1] + at[s][2] * vv[2];
  shB[slot][0][j] = zc[0]; shB[slot][1][j] = zc[1]; shB[slot][2][j] = zc[2];
  __syncthreads();  // #2

  // z2 = Zc @ Wz^T + bz + x
  const float bzj = bz[j];
  float z2a[3] = {bzj + x0, bzj + x1, bzj + x2};
  {
    const float* wzr = Wz + j * 32;
#pragma unroll 8
    for (int k = 0; k < 32; ++k) {
      const float w = wzr[k];
      z2a[0] += w * shB[slot][0][k];
      z2a[1] += w * shB[slot][1][k];
      z2a[2] += w * shB[slot][2][k];
    }
  }

  float zn[3];
  ln3(z2a[0], z2a[1], z2a[2], g2, be2, zn);
  shA[slot][0][j] = zn[0]; shA[slot][1][j] = zn[1]; shA[slot][2][j] = zn[2];
  __syncthreads();  // #3

  // Z = Zn @ Wff^T + bff + z2
  const float bffj = bff[j];
  float Za[3] = {bffj + z2a[0], bffj + z2a[1], bffj + z2a[2]};
  {
    const float* wfr = Wff + j * 32;
#pragma unroll 8
    for (int k = 0; k < 32; ++k) {
      const float w = wfr[k];
      Za[0] += w * shA[slot][0][k];
      Za[1] += w * shA[slot][1][k];
      Za[2] += w * shA[slot][2][k];
    }
  }
  shB[slot][0][j] = Za[0]; shB[slot][1][j] = Za[1]; shB[slot][2][j] = Za[2];
  __syncthreads();  // #4

  // head: p1 = relu(flat @ Wp1^T + bp1), logits = p1 @ Wp2^T + bp2, softmax
  float p = bp1[j];
  {
    const float* wpr = Wp1 + j * 96;
#pragma unroll
    for (int s = 0; s < 3; ++s)
#pragma unroll 8
      for (int k = 0; k < 32; ++k) p += wpr[s * 32 + k] * shB[slot][s][k];
  }
  p = fmaxf(p, 0.0f);
  float l0 = Wp2[j] * p, l1 = Wp2[32 + j] * p;
  l0 += __shfl_xor(l0, 1); l0 += __shfl_xor(l0, 2); l0 += __shfl_xor(l0, 4);
  l0 += __shfl_xor(l0, 8); l0 += __shfl_xor(l0, 16);
  l1 += __shfl_xor(l1, 1); l1 += __shfl_xor(l1, 2); l1 += __shfl_xor(l1, 4);
  l1 += __shfl_xor(l1, 8); l1 += __shfl_xor(l1, 16);
  l0 += bp2[0]; l1 += bp2[1];
  const float mx = fmaxf(l0, l1);
  const float e0 = __expf(l0 - mx), e1 = __expf(l1 - mx);
  const float inv = __fdividef(1.0f, e0 + e1);
  if (j == 0) {
    out[(size_t)n * 2 + 0] = e0 * inv;
    out[(size_t)n * 2 + 1] = e1 * inv;
  }
}

// ---------------------------------------------------------------------------
extern "C" void kernel_launch(void* const* d_in, const int* in_sizes, int n_in,
                              void* d_out, int out_size, void* d_ws,
                              size_t ws_size, hipStream_t stream) {
  const float* l    = (const float*)d_in[0];
  const float* a    = (const float*)d_in[1];
  const float* v    = (const float*)d_in[2];
  const float* lW1  = (const float*)d_in[3];
  const float* lb1  = (const float*)d_in[4];
  const float* lW2  = (const float*)d_in[5];
  const float* lb2  = (const float*)d_in[6];
  const float* aWih = (const float*)d_in[7];
  const float* aWhh = (const float*)d_in[8];
  const float* abih = (const float*)d_in[9];
  const float* abhh = (const float*)d_in[10];
  const float* aWo  = (const float*)d_in[11];
  const float* abo  = (const float*)d_in[12];
  const float* vWih = (const float*)d_in[13];
  const float* vWhh = (const float*)d_in[14];
  const float* vbih = (const float*)d_in[15];
  const float* vbhh = (const float*)d_in[16];
  const float* vWo  = (const float*)d_in[17];
  const float* vbo  = (const float*)d_in[18];
  const float* Wq   = (const float*)d_in[19];
  const float* bq   = (const float*)d_in[20];
  const float* Wk   = (const float*)d_in[21];
  const float* bk   = (const float*)d_in[22];
  const float* Wv   = (const float*)d_in[23];
  const float* bv   = (const float*)d_in[24];
  const float* Wz   = (const float*)d_in[25];
  const float* bz   = (const float*)d_in[26];
  const float* Wff  = (const float*)d_in[27];
  const float* bff  = (const float*)d_in[28];
  const float* g1   = (const float*)d_in[29];
  const float* be1  = (const float*)d_in[30];
  const float* g2   = (const float*)d_in[31];
  const float* be2  = (const float*)d_in[32];
  const float* Wp1  = (const float*)d_in[33];
  const float* bp1  = (const float*)d_in[34];
  const float* Wp2  = (const float*)d_in[35];
  const float* bp2  = (const float*)d_in[36];

  float* out = (float*)d_out;
  float* ws = (float*)d_ws;
  float* lfw = ws;                     // [4096,32]
  float* afw = ws + 4096 * 32;         // [4096,32]
  float* vfw = ws + 2 * 4096 * 32;     // [4096,32]

  hipLaunchKernelGGL(lstm_both, dim3(512), dim3(64), 0, stream, a, v, aWih,
                     aWhh, abih, abhh, aWo, abo, vWih, vWhh, vbih, vbhh, vWo,
                     vbo, afw, vfw);
  hipLaunchKernelGGL(lf_kernel, dim3(256), dim3(256), 0, stream, l, lW1, lb1,
                     lW2, lb2, lfw);
  hipLaunchKernelGGL(head_kernel, dim3(512), dim3(256), 0, stream, lfw, afw,
                     vfw, Wq, bq, Wk, bk, Wv, bv, Wz, bz, Wff, bff, g1, be1,
                     g2, be2, Wp1, bp1, Wp2, bp2, out);
}

// Round 2
// 508.318 us; speedup vs baseline: 1.2857x; 1.2857x over previous
//
#include <hip/hip_runtime.h>

// ---------------------------------------------------------------------------
// Fused multimodal net: l-MLP + 2 LSTMs (MFMA bf16, LDS-staged) + tiny
// transformer head. N=4096, T=256, DA=74, DV=47, hidden=32.
//
// LSTM structure: block = 128 threads = 2 waves, 16 samples.
// Wave w owns units w*16..w*16+15  => gate tiles {w, 2+w, 4+w, 6+w} (i,f,g,o
// of the same units -> elementwise update is register-local; C-layout of h
// equals the B-fragment layout so own-tile recurrence never leaves registers).
// Cross-wave: 16-wide h-tile exchanged via double-buffered LDS, 1 barrier/step.
// x staged coalesced via global_load_lds (TS=4 steps, double buffer),
// vmcnt(0) only at stage boundaries; raw s_barrier (no vmcnt drain).
// ---------------------------------------------------------------------------

typedef float float4v __attribute__((ext_vector_type(4)));
typedef short short4v __attribute__((ext_vector_type(4)));

#define N_SAMPLES 4096
#define T_STEPS 256
#define TS 4
#define NST (T_STEPS / TS)

#define LGKM0 asm volatile("s_waitcnt lgkmcnt(0)" ::: "memory")
#define VM0 asm volatile("s_waitcnt vmcnt(0)" ::: "memory")

__device__ __forceinline__ short bf16r(float f) {
  unsigned u = __float_as_uint(f);
  u += 0x7FFFu + ((u >> 16) & 1u);
  return (short)(u >> 16);
}
__device__ __forceinline__ float sigmoidf_(float v) {
  return __fdividef(1.0f, 1.0f + __expf(-v));
}
__device__ __forceinline__ float tanhf_fast(float v) {
  return 1.0f - __fdividef(2.0f, __expf(2.0f * v) + 1.0f);
}
__device__ __forceinline__ float4v mfma16(short4v a, short4v b, float4v c) {
  return __builtin_amdgcn_mfma_f32_16x16x16bf16_1k(a, b, c, 0, 0, 0);
}

// async global->LDS, 16B per lane; lds base wave-uniform, HW adds lane*16
__device__ __forceinline__ void gld16(const float* g, float* l) {
  __builtin_amdgcn_global_load_lds(
      (const __attribute__((address_space(1))) unsigned int*)g,
      (__attribute__((address_space(3))) unsigned int*)l, 16, 0, 0);
}

// LDS bytes: xbuf 2*TS*16*74*4 = 37888, H 2*2*16*40 = 2560, pad 256
#define SMEM_BYTES (2 * TS * 16 * 74 * 4 + 2560 + 256)

template <int D, int NKX>
__device__ void lstm2(const float* __restrict__ x,
                      const float* __restrict__ Wih,
                      const float* __restrict__ Whh,
                      const float* __restrict__ bih,
                      const float* __restrict__ bhh,
                      const float* __restrict__ Wo,
                      const float* __restrict__ bo,
                      float* __restrict__ outf, int n0, char* smem) {
  constexpr int UPS = (16 * D) / 4;  // 16B units per step
  constexpr int FPS = 16 * D;        // floats per step
  constexpr int NKT = NKX + 2;
  static_assert(UPS % 128 <= 64, "tail must fit one wave");

  float* xbuf = (float*)smem;                                   // [2][TS][FPS]
  unsigned short* Hu = (unsigned short*)(smem + 2 * TS * FPS * 4);
  // H index (hb, tile, colc): ((hb*2+tile)*16+colc)*20 ushorts (40B rows)

  const int tid = threadIdx.x;
  const int wid = tid >> 6;
  const int lane = tid & 63;
  const int colc = lane & 15;
  const int q = lane >> 4;

  auto stage = [&](int s) {
    const int t0 = s * TS;
    const float* gbase = x + (size_t)t0 * N_SAMPLES * D + (size_t)n0 * D;
    float* lbase = xbuf + (s & 1) * (TS * FPS);
#pragma unroll
    for (int ts = 0; ts < TS; ++ts) {
      const float* gs = gbase + (size_t)ts * N_SAMPLES * D;
      float* lsv = lbase + ts * FPS;
#pragma unroll
      for (int r = 0; r < UPS / 128; ++r)
        gld16(gs + (r * 128 + wid * 64 + lane) * 4,
              lsv + (r * 128 + wid * 64) * 4);
      constexpr int rem = UPS % 128;
      if (rem) {
        if (wid == 0 && lane < rem)
          gld16(gs + ((UPS / 128) * 128 + lane) * 4,
                lsv + ((UPS / 128) * 128) * 4);
      }
    }
  };

  stage(0);  // issue first stage ASAP; weight loads overlap its latency

  // stationary weight A-fragments: 4 gate tiles (this wave's units)
  short4v wf[4][NKT];
#pragma unroll
  for (int g = 0; g < 4; ++g) {
    const int row = g * 32 + wid * 16 + colc;
    const float bsum = bih[row] + bhh[row];
    const float* wr = Wih + row * D;
#pragma unroll
    for (int kt = 0; kt < NKX; ++kt) {
      short4v s;
#pragma unroll
      for (int e = 0; e < 4; ++e) {
        const int d = kt * 16 + q * 4 + e;
        float val = (d < D) ? wr[d] : (d == D ? bsum : 0.0f);
        s[e] = bf16r(val);
      }
      wf[g][kt] = s;
    }
    const float* hr = Whh + row * 32;
#pragma unroll
    for (int ht = 0; ht < 2; ++ht) {
      short4v s;
#pragma unroll
      for (int e = 0; e < 4; ++e) s[e] = bf16r(hr[ht * 16 + q * 4 + e]);
      wf[g][NKX + ht] = s;
    }
  }

  // zero both H buffers (640 floats)
  {
    float* Hf = (float*)Hu;
    for (int i = tid; i < 640; i += 128) Hf[i] = 0.0f;
  }
  VM0;    // stage-0 loads landed
  LGKM0;  // H zeros visible
  __builtin_amdgcn_s_barrier();
  __builtin_amdgcn_sched_barrier(0);

  float c_st[4] = {0.0f, 0.0f, 0.0f, 0.0f};
  short4v hOwn = {0, 0, 0, 0};

  for (int sgl = 0; sgl < NST; ++sgl) {
    if (sgl + 1 < NST) stage(sgl + 1);
    const float* xb = xbuf + (sgl & 1) * (TS * FPS);
#pragma unroll
    for (int ts = 0; ts < TS; ++ts) {
      const int t = sgl * TS + ts;
      const int hb = t & 1;
      const float* xs = xb + ts * FPS + colc * D;

      // x fragments from LDS (4 consecutive floats per k-tile)
      short4v xB[NKX];
#pragma unroll
      for (int kt = 0; kt < NKX; ++kt) {
        short4v sv;
        if (kt == NKX - 1) {
#pragma unroll
          for (int e = 0; e < 4; ++e) {
            const int d = kt * 16 + q * 4 + e;
            const float f = xs[d];
            sv[e] = bf16r((d < D) ? f : (d == D ? 1.0f : 0.0f));
          }
        } else {
#pragma unroll
          for (int e = 0; e < 4; ++e) sv[e] = bf16r(xs[kt * 16 + q * 4 + e]);
        }
        xB[kt] = sv;
      }

      // other wave's h tile from LDS
      const short4v hOth = *(const short4v*)(
          Hu + ((hb * 2 + (1 - wid)) * 16 + colc) * 20 + q * 4);

      float4v acc[4];
#pragma unroll
      for (int g = 0; g < 4; ++g) {
        float4v a4 = {0.0f, 0.0f, 0.0f, 0.0f};
#pragma unroll
        for (int kt = 0; kt < NKX; ++kt) a4 = mfma16(wf[g][kt], xB[kt], a4);
        a4 = mfma16(wf[g][NKX + wid], hOwn, a4);
        a4 = mfma16(wf[g][NKX + (1 - wid)], hOth, a4);
        acc[g] = a4;
      }

      // elementwise update (i,f,g,o of same unit live in the same lane)
#pragma unroll
      for (int r = 0; r < 4; ++r) {
        const float iv = sigmoidf_(acc[0][r]);
        const float fv = sigmoidf_(acc[1][r]);
        const float gv = tanhf_fast(acc[2][r]);
        const float ov = sigmoidf_(acc[3][r]);
        const float cv = fv * c_st[r] + iv * gv;
        c_st[r] = cv;
        hOwn[r] = bf16r(ov * tanhf_fast(cv));
      }

      // publish own h tile for t+1
      *(short4v*)(Hu + (((1 - hb) * 2 + wid) * 16 + colc) * 20 + q * 4) = hOwn;

      if (ts == TS - 1) { VM0; }  // next-stage loads landed (issued TS ago)
      LGKM0;                      // h writes visible
      __builtin_amdgcn_s_barrier();
      __builtin_amdgcn_sched_barrier(0);
    }
  }

  // epilogue: out rows wid*16..wid*16+15 ; final h: own regs + H[0] other
  short4v hT0, hT1;
  if (wid == 0) {
    hT0 = hOwn;
    hT1 = *(const short4v*)(Hu + ((0 * 2 + 1) * 16 + colc) * 20 + q * 4);
  } else {
    hT1 = hOwn;
    hT0 = *(const short4v*)(Hu + ((0 * 2 + 0) * 16 + colc) * 20 + q * 4);
  }
  const int row = wid * 16 + colc;
  const float* wor = Wo + row * 32;
  short4v w0, w1;
#pragma unroll
  for (int e = 0; e < 4; ++e) {
    w0[e] = bf16r(wor[q * 4 + e]);
    w1[e] = bf16r(wor[16 + q * 4 + e]);
  }
  float4v o4 = {0.0f, 0.0f, 0.0f, 0.0f};
  o4 = mfma16(w0, hT0, o4);
  o4 = mfma16(w1, hT1, o4);
  float4v res;
#pragma unroll
  for (int r = 0; r < 4; ++r)
    res[r] = fmaxf(o4[r] + bo[wid * 16 + q * 4 + r], 0.0f);
  *(float4v*)(outf + (size_t)(n0 + colc) * 32 + wid * 16 + q * 4) = res;
}

__global__ __launch_bounds__(128) void lstm_both(
    const float* __restrict__ a, const float* __restrict__ v,
    const float* __restrict__ aWih, const float* __restrict__ aWhh,
    const float* __restrict__ abih, const float* __restrict__ abhh,
    const float* __restrict__ aWo, const float* __restrict__ abo,
    const float* __restrict__ vWih, const float* __restrict__ vWhh,
    const float* __restrict__ vbih, const float* __restrict__ vbhh,
    const float* __restrict__ vWo, const float* __restrict__ vbo,
    float* __restrict__ afw, float* __restrict__ vfw) {
  __shared__ __align__(16) char smem[SMEM_BYTES];
  const int b = blockIdx.x;
  if (b < 256)
    lstm2<74, 5>(a, aWih, aWhh, abih, abhh, aWo, abo, afw, b * 16, smem);
  else
    lstm2<47, 3>(v, vWih, vWhh, vbih, vbhh, vWo, vbo, vfw, (b - 256) * 16,
                 smem);
}

// ---------------------------------------------------------------------------
// lf = relu(relu(l @ lW1^T + lb1) @ lW2^T + lb2)   [4096,768]->[4096,32]
// ---------------------------------------------------------------------------
__global__ __launch_bounds__(256) void lf_kernel(
    const float* __restrict__ l, const float* __restrict__ lW1,
    const float* __restrict__ lb1, const float* __restrict__ lW2,
    const float* __restrict__ lb2, float* __restrict__ lf) {
  __shared__ __align__(16) float lsh[16 * 768];
  __shared__ __align__(16) float h1sh[16 * 128];
  const int tid = threadIdx.x;
  const int n0 = blockIdx.x * 16;

  {
    const float4v* src = (const float4v*)(l + (size_t)n0 * 768);
    float4v* dst = (float4v*)lsh;
#pragma unroll
    for (int i = 0; i < 12; ++i) dst[tid + i * 256] = src[tid + i * 256];
  }
  __syncthreads();

  {
    const int u = tid & 127;
    const int sg = tid >> 7;
    float acc[8];
#pragma unroll
    for (int i = 0; i < 8; ++i) acc[i] = 0.0f;
    const float4v* wrow = (const float4v*)(lW1 + u * 768);
    for (int k4 = 0; k4 < 192; ++k4) {
      const float4v w = wrow[k4];
#pragma unroll
      for (int i = 0; i < 8; ++i) {
        const float4v xv = ((const float4v*)(lsh + (sg * 8 + i) * 768))[k4];
        acc[i] += w[0] * xv[0] + w[1] * xv[1] + w[2] * xv[2] + w[3] * xv[3];
      }
    }
    const float b = lb1[u];
#pragma unroll
    for (int i = 0; i < 8; ++i)
      h1sh[(sg * 8 + i) * 128 + u] = fmaxf(acc[i] + b, 0.0f);
  }
  __syncthreads();

  {
    const int u2 = tid & 31;
    const int sg2 = tid >> 5;
    float acc0 = 0.0f, acc1 = 0.0f;
    const float4v* w2 = (const float4v*)(lW2 + u2 * 128);
#pragma unroll
    for (int k4 = 0; k4 < 32; ++k4) {
      const float4v w = w2[k4];
      const float4v xa = ((const float4v*)(h1sh + sg2 * 128))[k4];
      const float4v xb = ((const float4v*)(h1sh + (sg2 + 8) * 128))[k4];
      acc0 += w[0] * xa[0] + w[1] * xa[1] + w[2] * xa[2] + w[3] * xa[3];
      acc1 += w[0] * xb[0] + w[1] * xb[1] + w[2] * xb[2] + w[3] * xb[3];
    }
    const float b2 = lb2[u2];
    lf[(size_t)(n0 + sg2) * 32 + u2] = fmaxf(acc0 + b2, 0.0f);
    lf[(size_t)(n0 + sg2 + 8) * 32 + u2] = fmaxf(acc1 + b2, 0.0f);
  }
}

// ---------------------------------------------------------------------------
// Transformer block + post-fusion head. 32 lanes/sample, 8 samples/block.
// ---------------------------------------------------------------------------
__global__ __launch_bounds__(256) void head_kernel(
    const float* __restrict__ lf, const float* __restrict__ af,
    const float* __restrict__ vf, const float* __restrict__ Wq,
    const float* __restrict__ bq, const float* __restrict__ Wk,
    const float* __restrict__ bk, const float* __restrict__ Wv,
    const float* __restrict__ bv, const float* __restrict__ Wz,
    const float* __restrict__ bz, const float* __restrict__ Wff,
    const float* __restrict__ bff, const float* __restrict__ g1,
    const float* __restrict__ be1, const float* __restrict__ g2,
    const float* __restrict__ be2, const float* __restrict__ Wp1,
    const float* __restrict__ bp1, const float* __restrict__ Wp2,
    const float* __restrict__ bp2, float* __restrict__ out) {
  __shared__ float shA[8][3][33];
  __shared__ float shB[8][3][33];
  const int tid = threadIdx.x;
  const int j = tid & 31;
  const int slot = tid >> 5;
  const int n = blockIdx.x * 8 + slot;
  const size_t off = (size_t)n * 32 + j;

  const float x0 = lf[off], x1 = af[off], x2 = vf[off];

  auto ln3 = [&](float a0, float a1, float a2, const float* g,
                 const float* be, float* o) {
    float s = a0 + a1 + a2;
    s += __shfl_xor(s, 1); s += __shfl_xor(s, 2); s += __shfl_xor(s, 4);
    s += __shfl_xor(s, 8); s += __shfl_xor(s, 16);
    const float mu = s * (1.0f / 96.0f);
    const float d0 = a0 - mu, d1 = a1 - mu, d2 = a2 - mu;
    float ss = d0 * d0 + d1 * d1 + d2 * d2;
    ss += __shfl_xor(ss, 1); ss += __shfl_xor(ss, 2); ss += __shfl_xor(ss, 4);
    ss += __shfl_xor(ss, 8); ss += __shfl_xor(ss, 16);
    const float rs = rsqrtf(ss * (1.0f / 96.0f) + 1e-5f);
    o[0] = d0 * rs * g[j] + be[j];
    o[1] = d1 * rs * g[32 + j] + be[32 + j];
    o[2] = d2 * rs * g[64 + j] + be[64 + j];
  };

  float z[3];
  ln3(x0, x1, x2, g1, be1, z);
  shA[slot][0][j] = z[0]; shA[slot][1][j] = z[1]; shA[slot][2][j] = z[2];
  __syncthreads();

  float qv[3], kv[3], vv[3];
  {
    const float bqj = bq[j], bkj = bk[j], bvj = bv[j];
    qv[0] = bqj; qv[1] = bqj; qv[2] = bqj;
    kv[0] = bkj; kv[1] = bkj; kv[2] = bkj;
    vv[0] = bvj; vv[1] = bvj; vv[2] = bvj;
    const float* wqr = Wq + j * 32;
    const float* wkr = Wk + j * 32;
    const float* wvr = Wv + j * 32;
#pragma unroll 8
    for (int k = 0; k < 32; ++k) {
      const float zz0 = shA[slot][0][k], zz1 = shA[slot][1][k],
                  zz2 = shA[slot][2][k];
      const float wq = wqr[k], wk_ = wkr[k], wv_ = wvr[k];
      qv[0] += wq * zz0;  qv[1] += wq * zz1;  qv[2] += wq * zz2;
      kv[0] += wk_ * zz0; kv[1] += wk_ * zz1; kv[2] += wk_ * zz2;
      vv[0] += wv_ * zz0; vv[1] += wv_ * zz1; vv[2] += wv_ * zz2;
    }
  }

  float at[3][3];
#pragma unroll
  for (int s = 0; s < 3; ++s)
#pragma unroll
    for (int t2 = 0; t2 < 3; ++t2) {
      float p = qv[s] * kv[t2];
      p += __shfl_xor(p, 1); p += __shfl_xor(p, 2); p += __shfl_xor(p, 4);
      at[s][t2] = p;
    }
#pragma unroll
  for (int s = 0; s < 3; ++s) {
    const float m = fmaxf(fmaxf(at[s][0], at[s][1]), at[s][2]);
    const float e0 = __expf(at[s][0] - m), e1 = __expf(at[s][1] - m),
                e2 = __expf(at[s][2] - m);
    const float sc = 0.35355339059327373f * __fdividef(1.0f, e0 + e1 + e2);
    at[s][0] = e0 * sc; at[s][1] = e1 * sc; at[s][2] = e2 * sc;
  }
  float zc[3];
#pragma unroll
  for (int s = 0; s < 3; ++s)
    zc[s] = at[s][0] * vv[0] + at[s][1] * vv[1] + at[s][2] * vv[2];
  shB[slot][0][j] = zc[0]; shB[slot][1][j] = zc[1]; shB[slot][2][j] = zc[2];
  __syncthreads();

  const float bzj = bz[j];
  float z2a[3] = {bzj + x0, bzj + x1, bzj + x2};
  {
    const float* wzr = Wz + j * 32;
#pragma unroll 8
    for (int k = 0; k < 32; ++k) {
      const float w = wzr[k];
      z2a[0] += w * shB[slot][0][k];
      z2a[1] += w * shB[slot][1][k];
      z2a[2] += w * shB[slot][2][k];
    }
  }

  float zn[3];
  ln3(z2a[0], z2a[1], z2a[2], g2, be2, zn);
  shA[slot][0][j] = zn[0]; shA[slot][1][j] = zn[1]; shA[slot][2][j] = zn[2];
  __syncthreads();

  const float bffj = bff[j];
  float Za[3] = {bffj + z2a[0], bffj + z2a[1], bffj + z2a[2]};
  {
    const float* wfr = Wff + j * 32;
#pragma unroll 8
    for (int k = 0; k < 32; ++k) {
      const float w = wfr[k];
      Za[0] += w * shA[slot][0][k];
      Za[1] += w * shA[slot][1][k];
      Za[2] += w * shA[slot][2][k];
    }
  }
  shB[slot][0][j] = Za[0]; shB[slot][1][j] = Za[1]; shB[slot][2][j] = Za[2];
  __syncthreads();

  float p = bp1[j];
  {
    const float* wpr = Wp1 + j * 96;
#pragma unroll
    for (int s = 0; s < 3; ++s)
#pragma unroll 8
      for (int k = 0; k < 32; ++k) p += wpr[s * 32 + k] * shB[slot][s][k];
  }
  p = fmaxf(p, 0.0f);
  float l0 = Wp2[j] * p, l1 = Wp2[32 + j] * p;
  l0 += __shfl_xor(l0, 1); l0 += __shfl_xor(l0, 2); l0 += __shfl_xor(l0, 4);
  l0 += __shfl_xor(l0, 8); l0 += __shfl_xor(l0, 16);
  l1 += __shfl_xor(l1, 1); l1 += __shfl_xor(l1, 2); l1 += __shfl_xor(l1, 4);
  l1 += __shfl_xor(l1, 8); l1 += __shfl_xor(l1, 16);
  l0 += bp2[0]; l1 += bp2[1];
  const float mx = fmaxf(l0, l1);
  const float e0 = __expf(l0 - mx), e1 = __expf(l1 - mx);
  const float inv = __fdividef(1.0f, e0 + e1);
  if (j == 0) {
    out[(size_t)n * 2 + 0] = e0 * inv;
    out[(size_t)n * 2 + 1] = e1 * inv;
  }
}

// ---------------------------------------------------------------------------
extern "C" void kernel_launch(void* const* d_in, const int* in_sizes, int n_in,
                              void* d_out, int out_size, void* d_ws,
                              size_t ws_size, hipStream_t stream) {
  const float* l    = (const float*)d_in[0];
  const float* a    = (const float*)d_in[1];
  const float* v    = (const float*)d_in[2];
  const float* lW1  = (const float*)d_in[3];
  const float* lb1  = (const float*)d_in[4];
  const float* lW2  = (const float*)d_in[5];
  const float* lb2  = (const float*)d_in[6];
  const float* aWih = (const float*)d_in[7];
  const float* aWhh = (const float*)d_in[8];
  const float* abih = (const float*)d_in[9];
  const float* abhh = (const float*)d_in[10];
  const float* aWo  = (const float*)d_in[11];
  const float* abo  = (const float*)d_in[12];
  const float* vWih = (const float*)d_in[13];
  const float* vWhh = (const float*)d_in[14];
  const float* vbih = (const float*)d_in[15];
  const float* vbhh = (const float*)d_in[16];
  const float* vWo  = (const float*)d_in[17];
  const float* vbo  = (const float*)d_in[18];
  const float* Wq   = (const float*)d_in[19];
  const float* bq   = (const float*)d_in[20];
  const float* Wk   = (const float*)d_in[21];
  const float* bk   = (const float*)d_in[22];
  const float* Wv   = (const float*)d_in[23];
  const float* bv   = (const float*)d_in[24];
  const float* Wz   = (const float*)d_in[25];
  const float* bz   = (const float*)d_in[26];
  const float* Wff  = (const float*)d_in[27];
  const float* bff  = (const float*)d_in[28];
  const float* g1   = (const float*)d_in[29];
  const float* be1  = (const float*)d_in[30];
  const float* g2   = (const float*)d_in[31];
  const float* be2  = (const float*)d_in[32];
  const float* Wp1  = (const float*)d_in[33];
  const float* bp1  = (const float*)d_in[34];
  const float* Wp2  = (const float*)d_in[35];
  const float* bp2  = (const float*)d_in[36];

  float* out = (float*)d_out;
  float* ws = (float*)d_ws;
  float* lfw = ws;
  float* afw = ws + 4096 * 32;
  float* vfw = ws + 2 * 4096 * 32;

  hipLaunchKernelGGL(lstm_both, dim3(512), dim3(128), 0, stream, a, v, aWih,
                     aWhh, abih, abhh, aWo, abo, vWih, vWhh, vbih, vbhh, vWo,
                     vbo, afw, vfw);
  hipLaunchKernelGGL(lf_kernel, dim3(256), dim3(256), 0, stream, l, lW1, lb1,
                     lW2, lb2, lfw);
  hipLaunchKernelGGL(head_kernel, dim3(512), dim3(256), 0, stream, lfw, afw,
                     vfw, Wq, bq, Wk, bk, Wv, bv, Wz, bz, Wff, bff, g1, be1,
                     g2, be2, Wp1, bp1, Wp2, bp2, out);
}

// Round 3
// 438.423 us; speedup vs baseline: 1.4907x; 1.1594x over previous
//
#include <hip/hip_runtime.h>

// ---------------------------------------------------------------------------
// Fused multimodal net: l-MLP + 2 LSTMs (MFMA bf16, LDS-staged) + tiny
// transformer head. N=4096, T=256, DA=74, DV=47, hidden=32.
//
// LSTM: block = 256 threads = 4 waves, 16 samples.
// Gate-interleaved row mapping: MFMA row r -> gate (r&3), unit base+(r>>2).
// Wave w owns tiles tau = w*2+{0,1} (units 4tau..4tau+3); lane (q,c) regs
// 0..3 = i,f,g,o of unit 4tau+q, sample c  => elementwise update lane-local.
// h round-trips LDS (ping-pong buffers, 1 barrier/step, all 4 waves).
// x staged f32 via global_load_lds (TS=4 steps double-buffered; wave w
// stages step g*TS+w); vmcnt(0) only at stage boundaries.
// f32->bf16 via v_cvt_pk_bf16_f32 (1 op / 2 values).
// ---------------------------------------------------------------------------

typedef float float4v __attribute__((ext_vector_type(4)));
typedef float float2v __attribute__((ext_vector_type(2)));
typedef short short4v __attribute__((ext_vector_type(4)));

#define N_SAMPLES 4096
#define T_STEPS 256
#define TS 4
#define NST (T_STEPS / TS)
#define HSTR 36  // ushorts per sample row in H (32 units + pad)

#define LGKM0 asm volatile("s_waitcnt lgkmcnt(0)" ::: "memory")
#define VM0 asm volatile("s_waitcnt vmcnt(0)" ::: "memory")

__device__ __forceinline__ short bf16r(float f) {
  unsigned u = __float_as_uint(f);
  u += 0x7FFFu + ((u >> 16) & 1u);
  return (short)(u >> 16);
}
__device__ __forceinline__ unsigned cvt_pk_bf16(float lo, float hi) {
  unsigned r;
  asm("v_cvt_pk_bf16_f32 %0, %1, %2" : "=v"(r) : "v"(lo), "v"(hi));
  return r;
}
__device__ __forceinline__ float sigmoidf_(float v) {
  return __fdividef(1.0f, 1.0f + __expf(-v));
}
__device__ __forceinline__ float tanhf_fast(float v) {
  return 1.0f - __fdividef(2.0f, __expf(2.0f * v) + 1.0f);
}
__device__ __forceinline__ float4v mfma16(short4v a, short4v b, float4v c) {
  return __builtin_amdgcn_mfma_f32_16x16x16bf16_1k(a, b, c, 0, 0, 0);
}
__device__ __forceinline__ void gld16(const float* g, float* l) {
  __builtin_amdgcn_global_load_lds(
      (const __attribute__((address_space(1))) unsigned int*)g,
      (__attribute__((address_space(3))) unsigned int*)l, 16, 0, 0);
}

// LDS: xbuf 2*TS*16*74*4 = 37888 + pad 64 + H 2*16*36*2 = 2304  => 40256
#define SMEM_BYTES (2 * TS * 16 * 74 * 4 + 64 + 2 * 16 * HSTR * 2)

template <int D, int NKX>
__device__ void lstm4(const float* __restrict__ x,
                      const float* __restrict__ Wih,
                      const float* __restrict__ Whh,
                      const float* __restrict__ bih,
                      const float* __restrict__ bhh,
                      const float* __restrict__ Wo,
                      const float* __restrict__ bo,
                      float* __restrict__ outf, int n0, char* smem) {
  constexpr int FPS = 16 * D;   // floats per step slot
  constexpr int UPS = FPS / 4;  // 16B units per step

  float* xbuf = (float*)smem;  // [2][TS][FPS]
  unsigned short* Hu = (unsigned short*)(smem + 2 * TS * FPS * 4 + 64);

  const int tid = threadIdx.x;
  const int wid = tid >> 6;   // 0..3
  const int lane = tid & 63;
  const int colc = lane & 15; // sample col
  const int q = lane >> 4;    // k-quad / unit-within-tile

  // wave w stages step g*TS+w (one full step slot, linear dest)
  auto stage = [&](int g) {
    const int t = g * TS + wid;
    const float* gs = x + (size_t)t * (N_SAMPLES * D) + (size_t)n0 * D;
    float* ls = xbuf + (g & 1) * (TS * FPS) + wid * FPS;
#pragma unroll
    for (int r = 0; r < UPS / 64; ++r)
      gld16(gs + (r * 64 + lane) * 4, ls + r * 64 * 4);
    constexpr int rem = UPS % 64;
    if (rem) {
      if (lane < rem)
        gld16(gs + ((UPS / 64) * 64 + lane) * 4, ls + (UPS / 64) * 64 * 4);
    }
  };

  stage(0);  // overlap weight loading with first-stage HBM latency

  // stationary weight A-frags; row rr=colc -> gate row (rr&3)*32+tau*4+(rr>>2)
  short4v wfx[2][NKX], wfh[2][2];
#pragma unroll
  for (int T = 0; T < 2; ++T) {
    const int tau = wid * 2 + T;
    const int G = (colc & 3) * 32 + tau * 4 + (colc >> 2);
    const float bsum = bih[G] + bhh[G];
    const float* wr = Wih + G * D;
#pragma unroll
    for (int kt = 0; kt < NKX; ++kt) {
      short4v s;
#pragma unroll
      for (int e = 0; e < 4; ++e) {
        const int d = kt * 16 + q * 4 + e;
        const float val = (d < D) ? wr[d] : ((d == D) ? bsum : 0.0f);
        s[e] = bf16r(val);
      }
      wfx[T][kt] = s;
    }
    const float* hr = Whh + G * 32;
#pragma unroll
    for (int ht = 0; ht < 2; ++ht) {
      short4v s;
#pragma unroll
      for (int e = 0; e < 4; ++e) s[e] = bf16r(hr[ht * 16 + q * 4 + e]);
      wfh[T][ht] = s;
    }
  }

  // zero both H buffers (576 dwords)
  {
    unsigned* Hz = (unsigned*)Hu;
    for (int i = tid; i < (2 * 16 * HSTR) / 2; i += 256) Hz[i] = 0;
  }
  VM0;
  LGKM0;
  __builtin_amdgcn_s_barrier();
  __builtin_amdgcn_sched_barrier(0);

  float c_st[2] = {0.0f, 0.0f};

  for (int g = 0; g < NST; ++g) {
    if (g + 1 < NST) stage(g + 1);
    const float* xb = xbuf + (g & 1) * (TS * FPS);
#pragma unroll
    for (int ts = 0; ts < TS; ++ts) {
      const int t = g * TS + ts;
      const int pb = t & 1;  // read buffer (holds h[t-1])

      // h B-frags (all 32 units) from LDS
      const unsigned short* hp = Hu + pb * (16 * HSTR) + colc * HSTR;
      const short4v hB0 = *(const short4v*)(hp + q * 4);
      const short4v hB1 = *(const short4v*)(hp + 16 + q * 4);

      // x B-frags from LDS f32, cvt_pk to bf16
      const float* xs = xb + ts * FPS + colc * D;
      short4v xB[NKX];
#pragma unroll
      for (int kt = 0; kt < NKX; ++kt) {
        const float* p = xs + kt * 16 + q * 4;
        const float2v lo = *(const float2v*)(p);
        const float2v hi = *(const float2v*)(p + 2);
        float e0 = lo[0], e1 = lo[1], e2 = hi[0], e3 = hi[1];
        if (kt == NKX - 1) {  // bias column at d==D, zeros beyond
          const int kb = kt * 16 + q * 4;
          e0 = (kb + 0 < D) ? e0 : ((kb + 0 == D) ? 1.0f : 0.0f);
          e1 = (kb + 1 < D) ? e1 : ((kb + 1 == D) ? 1.0f : 0.0f);
          e2 = (kb + 2 < D) ? e2 : ((kb + 2 == D) ? 1.0f : 0.0f);
          e3 = (kb + 3 < D) ? e3 : ((kb + 3 == D) ? 1.0f : 0.0f);
        }
        union { short4v s; unsigned u[2]; } fr;
        fr.u[0] = cvt_pk_bf16(e0, e1);
        fr.u[1] = cvt_pk_bf16(e2, e3);
        xB[kt] = fr.s;
      }

      float4v acc[2];
#pragma unroll
      for (int T = 0; T < 2; ++T) {
        float4v a4 = {0.0f, 0.0f, 0.0f, 0.0f};
#pragma unroll
        for (int kt = 0; kt < NKX; ++kt) a4 = mfma16(wfx[T][kt], xB[kt], a4);
        a4 = mfma16(wfh[T][0], hB0, a4);
        a4 = mfma16(wfh[T][1], hB1, a4);
        acc[T] = a4;
      }

      // lane-local update: regs = i,f,g,o of unit (wid*2+T)*4+q
      unsigned short* hw = Hu + (1 - pb) * (16 * HSTR) + colc * HSTR;
#pragma unroll
      for (int T = 0; T < 2; ++T) {
        const float iv = sigmoidf_(acc[T][0]);
        const float fv = sigmoidf_(acc[T][1]);
        const float gv = tanhf_fast(acc[T][2]);
        const float ov = sigmoidf_(acc[T][3]);
        const float cv = fv * c_st[T] + iv * gv;
        c_st[T] = cv;
        hw[(wid * 2 + T) * 4 + q] = (unsigned short)bf16r(ov * tanhf_fast(cv));
      }

      if (ts == TS - 1) { VM0; }  // next stage landed (issued TS steps ago)
      LGKM0;
      __builtin_amdgcn_s_barrier();
      __builtin_amdgcn_sched_barrier(0);
    }
  }

  // epilogue: h[255] is in buf 0; out = relu(h @ Wo^T + bo), waves 0,1
  if (wid < 2) {
    const int T = wid;
    const unsigned short* hp = Hu + colc * HSTR;
    const short4v hB0 = *(const short4v*)(hp + q * 4);
    const short4v hB1 = *(const short4v*)(hp + 16 + q * 4);
    const float* wor = Wo + (16 * T + colc) * 32;
    short4v w0, w1;
#pragma unroll
    for (int e = 0; e < 4; ++e) {
      w0[e] = bf16r(wor[q * 4 + e]);
      w1[e] = bf16r(wor[16 + q * 4 + e]);
    }
    float4v o4 = {0.0f, 0.0f, 0.0f, 0.0f};
    o4 = mfma16(w0, hB0, o4);
    o4 = mfma16(w1, hB1, o4);
    float4v res;
#pragma unroll
    for (int r = 0; r < 4; ++r)
      res[r] = fmaxf(o4[r] + bo[16 * T + q * 4 + r], 0.0f);
    *(float4v*)(outf + (size_t)(n0 + colc) * 32 + 16 * T + q * 4) = res;
  }
}

__global__ __launch_bounds__(256) void lstm_both(
    const float* __restrict__ a, const float* __restrict__ v,
    const float* __restrict__ aWih, const float* __restrict__ aWhh,
    const float* __restrict__ abih, const float* __restrict__ abhh,
    const float* __restrict__ aWo, const float* __restrict__ abo,
    const float* __restrict__ vWih, const float* __restrict__ vWhh,
    const float* __restrict__ vbih, const float* __restrict__ vbhh,
    const float* __restrict__ vWo, const float* __restrict__ vbo,
    float* __restrict__ afw, float* __restrict__ vfw) {
  __shared__ __align__(16) char smem[SMEM_BYTES];
  const int b = blockIdx.x;
  if (b < 256)
    lstm4<74, 5>(a, aWih, aWhh, abih, abhh, aWo, abo, afw, b * 16, smem);
  else
    lstm4<47, 3>(v, vWih, vWhh, vbih, vbhh, vWo, vbo, vfw, (b - 256) * 16,
                 smem);
}

// ---------------------------------------------------------------------------
// lf = relu(relu(l @ lW1^T + lb1) @ lW2^T + lb2)   [4096,768]->[4096,32]
// ---------------------------------------------------------------------------
__global__ __launch_bounds__(256) void lf_kernel(
    const float* __restrict__ l, const float* __restrict__ lW1,
    const float* __restrict__ lb1, const float* __restrict__ lW2,
    const float* __restrict__ lb2, float* __restrict__ lf) {
  __shared__ __align__(16) float lsh[16 * 768];
  __shared__ __align__(16) float h1sh[16 * 128];
  const int tid = threadIdx.x;
  const int n0 = blockIdx.x * 16;

  {
    const float4v* src = (const float4v*)(l + (size_t)n0 * 768);
    float4v* dst = (float4v*)lsh;
#pragma unroll
    for (int i = 0; i < 12; ++i) dst[tid + i * 256] = src[tid + i * 256];
  }
  __syncthreads();

  {
    const int u = tid & 127;
    const int sg = tid >> 7;
    float acc[8];
#pragma unroll
    for (int i = 0; i < 8; ++i) acc[i] = 0.0f;
    const float4v* wrow = (const float4v*)(lW1 + u * 768);
    for (int k4 = 0; k4 < 192; ++k4) {
      const float4v w = wrow[k4];
#pragma unroll
      for (int i = 0; i < 8; ++i) {
        const float4v xv = ((const float4v*)(lsh + (sg * 8 + i) * 768))[k4];
        acc[i] += w[0] * xv[0] + w[1] * xv[1] + w[2] * xv[2] + w[3] * xv[3];
      }
    }
    const float b = lb1[u];
#pragma unroll
    for (int i = 0; i < 8; ++i)
      h1sh[(sg * 8 + i) * 128 + u] = fmaxf(acc[i] + b, 0.0f);
  }
  __syncthreads();

  {
    const int u2 = tid & 31;
    const int sg2 = tid >> 5;
    float acc0 = 0.0f, acc1 = 0.0f;
    const float4v* w2 = (const float4v*)(lW2 + u2 * 128);
#pragma unroll
    for (int k4 = 0; k4 < 32; ++k4) {
      const float4v w = w2[k4];
      const float4v xa = ((const float4v*)(h1sh + sg2 * 128))[k4];
      const float4v xb = ((const float4v*)(h1sh + (sg2 + 8) * 128))[k4];
      acc0 += w[0] * xa[0] + w[1] * xa[1] + w[2] * xa[2] + w[3] * xa[3];
      acc1 += w[0] * xb[0] + w[1] * xb[1] + w[2] * xb[2] + w[3] * xb[3];
    }
    const float b2 = lb2[u2];
    lf[(size_t)(n0 + sg2) * 32 + u2] = fmaxf(acc0 + b2, 0.0f);
    lf[(size_t)(n0 + sg2 + 8) * 32 + u2] = fmaxf(acc1 + b2, 0.0f);
  }
}

// ---------------------------------------------------------------------------
// Transformer block + post-fusion head. 32 lanes/sample, 8 samples/block.
// ---------------------------------------------------------------------------
__global__ __launch_bounds__(256) void head_kernel(
    const float* __restrict__ lf, const float* __restrict__ af,
    const float* __restrict__ vf, const float* __restrict__ Wq,
    const float* __restrict__ bq, const float* __restrict__ Wk,
    const float* __restrict__ bk, const float* __restrict__ Wv,
    const float* __restrict__ bv, const float* __restrict__ Wz,
    const float* __restrict__ bz, const float* __restrict__ Wff,
    const float* __restrict__ bff, const float* __restrict__ g1,
    const float* __restrict__ be1, const float* __restrict__ g2,
    const float* __restrict__ be2, const float* __restrict__ Wp1,
    const float* __restrict__ bp1, const float* __restrict__ Wp2,
    const float* __restrict__ bp2, float* __restrict__ out) {
  __shared__ float shA[8][3][33];
  __shared__ float shB[8][3][33];
  const int tid = threadIdx.x;
  const int j = tid & 31;
  const int slot = tid >> 5;
  const int n = blockIdx.x * 8 + slot;
  const size_t off = (size_t)n * 32 + j;

  const float x0 = lf[off], x1 = af[off], x2 = vf[off];

  auto ln3 = [&](float a0, float a1, float a2, const float* g,
                 const float* be, float* o) {
    float s = a0 + a1 + a2;
    s += __shfl_xor(s, 1); s += __shfl_xor(s, 2); s += __shfl_xor(s, 4);
    s += __shfl_xor(s, 8); s += __shfl_xor(s, 16);
    const float mu = s * (1.0f / 96.0f);
    const float d0 = a0 - mu, d1 = a1 - mu, d2 = a2 - mu;
    float ss = d0 * d0 + d1 * d1 + d2 * d2;
    ss += __shfl_xor(ss, 1); ss += __shfl_xor(ss, 2); ss += __shfl_xor(ss, 4);
    ss += __shfl_xor(ss, 8); ss += __shfl_xor(ss, 16);
    const float rs = rsqrtf(ss * (1.0f / 96.0f) + 1e-5f);
    o[0] = d0 * rs * g[j] + be[j];
    o[1] = d1 * rs * g[32 + j] + be[32 + j];
    o[2] = d2 * rs * g[64 + j] + be[64 + j];
  };

  float z[3];
  ln3(x0, x1, x2, g1, be1, z);
  shA[slot][0][j] = z[0]; shA[slot][1][j] = z[1]; shA[slot][2][j] = z[2];
  __syncthreads();

  float qv[3], kv[3], vv[3];
  {
    const float bqj = bq[j], bkj = bk[j], bvj = bv[j];
    qv[0] = bqj; qv[1] = bqj; qv[2] = bqj;
    kv[0] = bkj; kv[1] = bkj; kv[2] = bkj;
    vv[0] = bvj; vv[1] = bvj; vv[2] = bvj;
    const float* wqr = Wq + j * 32;
    const float* wkr = Wk + j * 32;
    const float* wvr = Wv + j * 32;
#pragma unroll 8
    for (int k = 0; k < 32; ++k) {
      const float zz0 = shA[slot][0][k], zz1 = shA[slot][1][k],
                  zz2 = shA[slot][2][k];
      const float wq = wqr[k], wk_ = wkr[k], wv_ = wvr[k];
      qv[0] += wq * zz0;  qv[1] += wq * zz1;  qv[2] += wq * zz2;
      kv[0] += wk_ * zz0; kv[1] += wk_ * zz1; kv[2] += wk_ * zz2;
      vv[0] += wv_ * zz0; vv[1] += wv_ * zz1; vv[2] += wv_ * zz2;
    }
  }

  float at[3][3];
#pragma unroll
  for (int s = 0; s < 3; ++s)
#pragma unroll
    for (int t2 = 0; t2 < 3; ++t2) {
      float p = qv[s] * kv[t2];
      p += __shfl_xor(p, 1); p += __shfl_xor(p, 2); p += __shfl_xor(p, 4);
      at[s][t2] = p;
    }
#pragma unroll
  for (int s = 0; s < 3; ++s) {
    const float m = fmaxf(fmaxf(at[s][0], at[s][1]), at[s][2]);
    const float e0 = __expf(at[s][0] - m), e1 = __expf(at[s][1] - m),
                e2 = __expf(at[s][2] - m);
    const float sc = 0.35355339059327373f * __fdividef(1.0f, e0 + e1 + e2);
    at[s][0] = e0 * sc; at[s][1] = e1 * sc; at[s][2] = e2 * sc;
  }
  float zc[3];
#pragma unroll
  for (int s = 0; s < 3; ++s)
    zc[s] = at[s][0] * vv[0] + at[s][1] * vv[1] + at[s][2] * vv[2];
  shB[slot][0][j] = zc[0]; shB[slot][1][j] = zc[1]; shB[slot][2][j] = zc[2];
  __syncthreads();

  const float bzj = bz[j];
  float z2a[3] = {bzj + x0, bzj + x1, bzj + x2};
  {
    const float* wzr = Wz + j * 32;
#pragma unroll 8
    for (int k = 0; k < 32; ++k) {
      const float w = wzr[k];
      z2a[0] += w * shB[slot][0][k];
      z2a[1] += w * shB[slot][1][k];
      z2a[2] += w * shB[slot][2][k];
    }
  }

  float zn[3];
  ln3(z2a[0], z2a[1], z2a[2], g2, be2, zn);
  shA[slot][0][j] = zn[0]; shA[slot][1][j] = zn[1]; shA[slot][2][j] = zn[2];
  __syncthreads();

  const float bffj = bff[j];
  float Za[3] = {bffj + z2a[0], bffj + z2a[1], bffj + z2a[2]};
  {
    const float* wfr = Wff + j * 32;
#pragma unroll 8
    for (int k = 0; k < 32; ++k) {
      const float w = wfr[k];
      Za[0] += w * shA[slot][0][k];
      Za[1] += w * shA[slot][1][k];
      Za[2] += w * shA[slot][2][k];
    }
  }
  shB[slot][0][j] = Za[0]; shB[slot][1][j] = Za[1]; shB[slot][2][j] = Za[2];
  __syncthreads();

  float p = bp1[j];
  {
    const float* wpr = Wp1 + j * 96;
#pragma unroll
    for (int s = 0; s < 3; ++s)
#pragma unroll 8
      for (int k = 0; k < 32; ++k) p += wpr[s * 32 + k] * shB[slot][s][k];
  }
  p = fmaxf(p, 0.0f);
  float l0 = Wp2[j] * p, l1 = Wp2[32 + j] * p;
  l0 += __shfl_xor(l0, 1); l0 += __shfl_xor(l0, 2); l0 += __shfl_xor(l0, 4);
  l0 += __shfl_xor(l0, 8); l0 += __shfl_xor(l0, 16);
  l1 += __shfl_xor(l1, 1); l1 += __shfl_xor(l1, 2); l1 += __shfl_xor(l1, 4);
  l1 += __shfl_xor(l1, 8); l1 += __shfl_xor(l1, 16);
  l0 += bp2[0]; l1 += bp2[1];
  const float mx = fmaxf(l0, l1);
  const float e0 = __expf(l0 - mx), e1 = __expf(l1 - mx);
  const float inv = __fdividef(1.0f, e0 + e1);
  if (j == 0) {
    out[(size_t)n * 2 + 0] = e0 * inv;
    out[(size_t)n * 2 + 1] = e1 * inv;
  }
}

// ---------------------------------------------------------------------------
extern "C" void kernel_launch(void* const* d_in, const int* in_sizes, int n_in,
                              void* d_out, int out_size, void* d_ws,
                              size_t ws_size, hipStream_t stream) {
  const float* l    = (const float*)d_in[0];
  const float* a    = (const float*)d_in[1];
  const float* v    = (const float*)d_in[2];
  const float* lW1  = (const float*)d_in[3];
  const float* lb1  = (const float*)d_in[4];
  const float* lW2  = (const float*)d_in[5];
  const float* lb2  = (const float*)d_in[6];
  const float* aWih = (const float*)d_in[7];
  const float* aWhh = (const float*)d_in[8];
  const float* abih = (const float*)d_in[9];
  const float* abhh = (const float*)d_in[10];
  const float* aWo  = (const float*)d_in[11];
  const float* abo  = (const float*)d_in[12];
  const float* vWih = (const float*)d_in[13];
  const float* vWhh = (const float*)d_in[14];
  const float* vbih = (const float*)d_in[15];
  const float* vbhh = (const float*)d_in[16];
  const float* vWo  = (const float*)d_in[17];
  const float* vbo  = (const float*)d_in[18];
  const float* Wq   = (const float*)d_in[19];
  const float* bq   = (const float*)d_in[20];
  const float* Wk   = (const float*)d_in[21];
  const float* bk   = (const float*)d_in[22];
  const float* Wv   = (const float*)d_in[23];
  const float* bv   = (const float*)d_in[24];
  const float* Wz   = (const float*)d_in[25];
  const float* bz   = (const float*)d_in[26];
  const float* Wff  = (const float*)d_in[27];
  const float* bff  = (const float*)d_in[28];
  const float* g1   = (const float*)d_in[29];
  const float* be1  = (const float*)d_in[30];
  const float* g2   = (const float*)d_in[31];
  const float* be2  = (const float*)d_in[32];
  const float* Wp1  = (const float*)d_in[33];
  const float* bp1  = (const float*)d_in[34];
  const float* Wp2  = (const float*)d_in[35];
  const float* bp2  = (const float*)d_in[36];

  float* out = (float*)d_out;
  float* ws = (float*)d_ws;
  float* lfw = ws;
  float* afw = ws + 4096 * 32;
  float* vfw = ws + 2 * 4096 * 32;

  hipLaunchKernelGGL(lstm_both, dim3(512), dim3(256), 0, stream, a, v, aWih,
                     aWhh, abih, abhh, aWo, abo, vWih, vWhh, vbih, vbhh, vWo,
                     vbo, afw, vfw);
  hipLaunchKernelGGL(lf_kernel, dim3(256), dim3(256), 0, stream, l, lW1, lb1,
                     lW2, lb2, lfw);
  hipLaunchKernelGGL(head_kernel, dim3(512), dim3(256), 0, stream, lfw, afw,
                     vfw, Wq, bq, Wk, bk, Wv, bv, Wz, bz, Wff, bff, g1, be1,
                     g2, be2, Wp1, bp1, Wp2, bp2, out);
}

// Round 4
// 422.832 us; speedup vs baseline: 1.5457x; 1.0369x over previous
//
#include <hip/hip_runtime.h>

// ---------------------------------------------------------------------------
// Fused multimodal net: l-MLP + 2 LSTMs (MFMA bf16, LDS-staged) + tiny
// transformer head. N=4096, T=256, DA=74, DV=47, hidden=32.
//
// LSTM: block = 256 threads = 4 waves, 16 samples, K=32 MFMA.
// Row map: MFMA row rho -> gate (rho&3), unit wid*8 + (rho>>2)*2 + T.
// Lane (q,colc) reg r of tile T = gate r of unit wid*8+q*2+T  => the two
// owned h values are adjacent shorts -> 1 cvt_pk + 1 ds_write_b32.
// Bias folded into MFMA C-init (f32). x tail masked by per-lane constants.
// x[t+1] fragments prefetched one step ahead (reads issued right after the
// barrier, converted at step tail) so only the h ds_read + 1 h-MFMA + trans
// chain sit in the synchronized window.
// ---------------------------------------------------------------------------

typedef float float4v __attribute__((ext_vector_type(4)));
typedef float float2v __attribute__((ext_vector_type(2)));
typedef short short4v __attribute__((ext_vector_type(4)));
typedef short short8v __attribute__((ext_vector_type(8)));

#define N_SAMPLES 4096
#define T_STEPS 256
#define TS 4
#define NST (T_STEPS / TS)
#define HSTR 40                 // shorts per sample row in H (32 units + pad)
#define HBUF (16 * HSTR)        // shorts per H buffer

#define LGKM0 asm volatile("s_waitcnt lgkmcnt(0)" ::: "memory")
#define VM0 asm volatile("s_waitcnt vmcnt(0)" ::: "memory")

__device__ __forceinline__ short bf16r(float f) {
  unsigned u = __float_as_uint(f);
  u += 0x7FFFu + ((u >> 16) & 1u);
  return (short)(u >> 16);
}
__device__ __forceinline__ unsigned cvt_pk_bf16(float lo, float hi) {
  unsigned r;
  asm("v_cvt_pk_bf16_f32 %0, %1, %2" : "=v"(r) : "v"(lo), "v"(hi));
  return r;
}
__device__ __forceinline__ float sigmoidf_(float v) {
  return __fdividef(1.0f, 1.0f + __expf(-v));
}
__device__ __forceinline__ float tanhf_fast(float v) {
  return 1.0f - __fdividef(2.0f, __expf(2.0f * v) + 1.0f);
}
__device__ __forceinline__ float4v mfma32(short8v a, short8v b, float4v c) {
  return __builtin_amdgcn_mfma_f32_16x16x32_bf16(a, b, c, 0, 0, 0);
}
__device__ __forceinline__ void gld16(const float* g, float* l) {
  __builtin_amdgcn_global_load_lds(
      (const __attribute__((address_space(1))) unsigned int*)g,
      (__attribute__((address_space(3))) unsigned int*)l, 16, 0, 0);
}

// LDS: xbuf 2*TS*16*74*4 = 37888 + pad 64 + H 2*640*2 = 2560  => 40512
#define SMEM_BYTES (2 * TS * 16 * 74 * 4 + 64 + 2 * HBUF * 2)

template <int D, int NK32>
__device__ void lstm5(const float* __restrict__ x,
                      const float* __restrict__ Wih,
                      const float* __restrict__ Whh,
                      const float* __restrict__ bih,
                      const float* __restrict__ bhh,
                      const float* __restrict__ Wo,
                      const float* __restrict__ bo,
                      float* __restrict__ outf, int n0, char* smem) {
  constexpr int FPS = 16 * D;   // floats per step slot (packed)
  constexpr int UPS = FPS / 4;  // 16B units per step

  float* xbuf = (float*)smem;  // [2][TS][FPS]
  unsigned short* Hu = (unsigned short*)(smem + 2 * TS * FPS * 4 + 64);

  const int tid = threadIdx.x;
  const int wid = tid >> 6;    // 0..3
  const int lane = tid & 63;
  const int colc = lane & 15;  // sample col / A-row
  const int q = lane >> 4;     // k-octet selector

  // wave w stages step g*TS+w (one full packed step slot, linear dest)
  auto stage = [&](int g) {
    const int t = g * TS + wid;
    const float* gs = x + (size_t)t * (N_SAMPLES * D) + (size_t)n0 * D;
    float* ls = xbuf + (g & 1) * (TS * FPS) + wid * FPS;
#pragma unroll
    for (int r = 0; r < UPS / 64; ++r)
      gld16(gs + (r * 64 + lane) * 4, ls + r * 64 * 4);
    constexpr int rem = UPS % 64;
    if (rem) {
      if (lane < rem)
        gld16(gs + ((UPS / 64) * 64 + lane) * 4, ls + (UPS / 64) * 64 * 4);
    }
  };

  stage(0);  // overlap weight/bias loading with first-stage HBM latency

  // tail mask for kt = NK32-1 (zero d >= D); dword j covers elems 2j,2j+1
  unsigned mm[4];
#pragma unroll
  for (int j = 0; j < 4; ++j) {
    const int d0 = (NK32 - 1) * 32 + q * 8 + 2 * j;
    mm[j] = ((d0 < D) ? 0xFFFFu : 0u) | ((d0 + 1 < D) ? 0xFFFF0000u : 0u);
  }

  // stationary weight A-frags. A row = colc -> gate row
  // G = (colc&3)*32 + wid*8 + (colc>>2)*2 + T ; k-map = q*8+e (same as B).
  short8v wfx[2][NK32], wfh[2];
  float4v binit[2];
#pragma unroll
  for (int T = 0; T < 2; ++T) {
    const int G = (colc & 3) * 32 + wid * 8 + ((colc >> 2) << 1) + T;
    const float* wr = Wih + G * D;
#pragma unroll
    for (int kt = 0; kt < NK32; ++kt) {
      short8v s;
#pragma unroll
      for (int e = 0; e < 8; ++e) {
        const int d = kt * 32 + q * 8 + e;
        s[e] = (d < D) ? bf16r(wr[d]) : (short)0;
      }
      wfx[T][kt] = s;
    }
    const float* hr = Whh + G * 32;
    short8v sh;
#pragma unroll
    for (int e = 0; e < 8; ++e) sh[e] = bf16r(hr[q * 8 + e]);
    wfh[T] = sh;
    // bias init: C reg r -> gate r of unit wid*8+q*2+T
    float4v b4;
#pragma unroll
    for (int r = 0; r < 4; ++r) {
      const int Gr = r * 32 + wid * 8 + q * 2 + T;
      b4[r] = bih[Gr] + bhh[Gr];
    }
    binit[T] = b4;
  }

  // zero both H buffers (640 dwords)
  {
    unsigned* Hz = (unsigned*)Hu;
    for (int i = tid; i < HBUF; i += 256) Hz[i] = 0;
  }
  VM0;    // stage-0 landed
  LGKM0;  // H zeros visible
  __builtin_amdgcn_s_barrier();
  __builtin_amdgcn_sched_barrier(0);

  float c_st[2] = {0.0f, 0.0f};

  // prologue: build x frags for t=0 from slot 0
  short8v xF[NK32];
  {
    const float* xs = xbuf + colc * D;
#pragma unroll
    for (int kt = 0; kt < NK32; ++kt) {
      const float* p = xs + kt * 32 + q * 8;
      const float2v r0 = *(const float2v*)(p);
      const float2v r1 = *(const float2v*)(p + 2);
      const float2v r2 = *(const float2v*)(p + 4);
      const float2v r3 = *(const float2v*)(p + 6);
      union { short8v s; unsigned u[4]; } fr;
      fr.u[0] = cvt_pk_bf16(r0[0], r0[1]);
      fr.u[1] = cvt_pk_bf16(r1[0], r1[1]);
      fr.u[2] = cvt_pk_bf16(r2[0], r2[1]);
      fr.u[3] = cvt_pk_bf16(r3[0], r3[1]);
      if (kt == NK32 - 1) {
#pragma unroll
        for (int j = 0; j < 4; ++j) fr.u[j] &= mm[j];
      }
      xF[kt] = fr.s;
    }
  }

  for (int g = 0; g < NST; ++g) {
    if (g + 1 < NST) stage(g + 1);
#pragma unroll
    for (int ts = 0; ts < TS; ++ts) {
      const int t = g * TS + ts;
      const int pb = t & 1;  // read buffer (holds h[t-1])

      if (ts == TS - 1) { VM0; }  // next stage landed before cross-buffer read

      // 1. h read (single b128, 16B-aligned, issued first)
      const short8v hB =
          *(const short8v*)(Hu + pb * HBUF + colc * HSTR);

      // 2. prefetch raw x[t+1] (reads overlap MFMA + trans below)
      const int tn = t + 1;
      const int slotn = ((tn >> 2) & 1) * TS + (tn & 3);
      const float* xsn = xbuf + slotn * FPS + colc * D;
      float2v nx[NK32][4];
#pragma unroll
      for (int kt = 0; kt < NK32; ++kt) {
        const float* p = xsn + kt * 32 + q * 8;
        nx[kt][0] = *(const float2v*)(p);
        nx[kt][1] = *(const float2v*)(p + 2);
        nx[kt][2] = *(const float2v*)(p + 4);
        nx[kt][3] = *(const float2v*)(p + 6);
      }

      // 3. gates = bias + Wih@x (+ Whh@h last, single dependent MFMA)
      float4v acc[2];
#pragma unroll
      for (int T = 0; T < 2; ++T) {
        float4v a4 = binit[T];
#pragma unroll
        for (int kt = 0; kt < NK32; ++kt) a4 = mfma32(wfx[T][kt], xF[kt], a4);
        a4 = mfma32(wfh[T], hB, a4);
        acc[T] = a4;
      }

      // 4. lane-local update; pack both h values into one dword
      float hv[2];
#pragma unroll
      for (int T = 0; T < 2; ++T) {
        const float iv = sigmoidf_(acc[T][0]);
        const float fv = sigmoidf_(acc[T][1]);
        const float gv = tanhf_fast(acc[T][2]);
        const float ov = sigmoidf_(acc[T][3]);
        const float cv = fv * c_st[T] + iv * gv;
        c_st[T] = cv;
        hv[T] = ov * tanhf_fast(cv);
      }
      *(unsigned*)(Hu + (1 - pb) * HBUF + colc * HSTR + wid * 8 + q * 2) =
          cvt_pk_bf16(hv[0], hv[1]);

      // 5. convert prefetched x[t+1] -> frags (reads have landed by now)
#pragma unroll
      for (int kt = 0; kt < NK32; ++kt) {
        union { short8v s; unsigned u[4]; } fr;
        fr.u[0] = cvt_pk_bf16(nx[kt][0][0], nx[kt][0][1]);
        fr.u[1] = cvt_pk_bf16(nx[kt][1][0], nx[kt][1][1]);
        fr.u[2] = cvt_pk_bf16(nx[kt][2][0], nx[kt][2][1]);
        fr.u[3] = cvt_pk_bf16(nx[kt][3][0], nx[kt][3][1]);
        if (kt == NK32 - 1) {
#pragma unroll
          for (int j = 0; j < 4; ++j) fr.u[j] &= mm[j];
        }
        xF[kt] = fr.s;
      }

      LGKM0;  // h write visible to all waves
      __builtin_amdgcn_s_barrier();
      __builtin_amdgcn_sched_barrier(0);
    }
  }

  // epilogue: h[255] in buffer 0; out = relu(h @ Wo^T + bo), waves 0,1
  if (wid < 2) {
    const short8v hB = *(const short8v*)(Hu + colc * HSTR);
    const float* wor = Wo + (16 * wid + colc) * 32;
    short8v w8;
#pragma unroll
    for (int e = 0; e < 8; ++e) w8[e] = bf16r(wor[q * 8 + e]);
    float4v o4 = {0.0f, 0.0f, 0.0f, 0.0f};
    o4 = mfma32(w8, hB, o4);
    float4v res;
#pragma unroll
    for (int r = 0; r < 4; ++r)
      res[r] = fmaxf(o4[r] + bo[16 * wid + q * 4 + r], 0.0f);
    *(float4v*)(outf + (size_t)(n0 + colc) * 32 + 16 * wid + q * 4) = res;
  }
}

__global__ __launch_bounds__(256, 2) void lstm_both(
    const float* __restrict__ a, const float* __restrict__ v,
    const float* __restrict__ aWih, const float* __restrict__ aWhh,
    const float* __restrict__ abih, const float* __restrict__ abhh,
    const float* __restrict__ aWo, const float* __restrict__ abo,
    const float* __restrict__ vWih, const float* __restrict__ vWhh,
    const float* __restrict__ vbih, const float* __restrict__ vbhh,
    const float* __restrict__ vWo, const float* __restrict__ vbo,
    float* __restrict__ afw, float* __restrict__ vfw) {
  __shared__ __align__(16) char smem[SMEM_BYTES];
  const int b = blockIdx.x;
  if (b < 256)
    lstm5<74, 3>(a, aWih, aWhh, abih, abhh, aWo, abo, afw, b * 16, smem);
  else
    lstm5<47, 2>(v, vWih, vWhh, vbih, vbhh, vWo, vbo, vfw, (b - 256) * 16,
                 smem);
}

// ---------------------------------------------------------------------------
// lf = relu(relu(l @ lW1^T + lb1) @ lW2^T + lb2)   [4096,768]->[4096,32]
// ---------------------------------------------------------------------------
__global__ __launch_bounds__(256) void lf_kernel(
    const float* __restrict__ l, const float* __restrict__ lW1,
    const float* __restrict__ lb1, const float* __restrict__ lW2,
    const float* __restrict__ lb2, float* __restrict__ lf) {
  __shared__ __align__(16) float lsh[16 * 768];
  __shared__ __align__(16) float h1sh[16 * 128];
  const int tid = threadIdx.x;
  const int n0 = blockIdx.x * 16;

  {
    const float4v* src = (const float4v*)(l + (size_t)n0 * 768);
    float4v* dst = (float4v*)lsh;
#pragma unroll
    for (int i = 0; i < 12; ++i) dst[tid + i * 256] = src[tid + i * 256];
  }
  __syncthreads();

  {
    const int u = tid & 127;
    const int sg = tid >> 7;
    float acc[8];
#pragma unroll
    for (int i = 0; i < 8; ++i) acc[i] = 0.0f;
    const float4v* wrow = (const float4v*)(lW1 + u * 768);
    for (int k4 = 0; k4 < 192; ++k4) {
      const float4v w = wrow[k4];
#pragma unroll
      for (int i = 0; i < 8; ++i) {
        const float4v xv = ((const float4v*)(lsh + (sg * 8 + i) * 768))[k4];
        acc[i] += w[0] * xv[0] + w[1] * xv[1] + w[2] * xv[2] + w[3] * xv[3];
      }
    }
    const float b = lb1[u];
#pragma unroll
    for (int i = 0; i < 8; ++i)
      h1sh[(sg * 8 + i) * 128 + u] = fmaxf(acc[i] + b, 0.0f);
  }
  __syncthreads();

  {
    const int u2 = tid & 31;
    const int sg2 = tid >> 5;
    float acc0 = 0.0f, acc1 = 0.0f;
    const float4v* w2 = (const float4v*)(lW2 + u2 * 128);
#pragma unroll
    for (int k4 = 0; k4 < 32; ++k4) {
      const float4v w = w2[k4];
      const float4v xa = ((const float4v*)(h1sh + sg2 * 128))[k4];
      const float4v xb = ((const float4v*)(h1sh + (sg2 + 8) * 128))[k4];
      acc0 += w[0] * xa[0] + w[1] * xa[1] + w[2] * xa[2] + w[3] * xa[3];
      acc1 += w[0] * xb[0] + w[1] * xb[1] + w[2] * xb[2] + w[3] * xb[3];
    }
    const float b2 = lb2[u2];
    lf[(size_t)(n0 + sg2) * 32 + u2] = fmaxf(acc0 + b2, 0.0f);
    lf[(size_t)(n0 + sg2 + 8) * 32 + u2] = fmaxf(acc1 + b2, 0.0f);
  }
}

// ---------------------------------------------------------------------------
// Transformer block + post-fusion head. 32 lanes/sample, 8 samples/block.
// ---------------------------------------------------------------------------
__global__ __launch_bounds__(256) void head_kernel(
    const float* __restrict__ lf, const float* __restrict__ af,
    const float* __restrict__ vf, const float* __restrict__ Wq,
    const float* __restrict__ bq, const float* __restrict__ Wk,
    const float* __restrict__ bk, const float* __restrict__ Wv,
    const float* __restrict__ bv, const float* __restrict__ Wz,
    const float* __restrict__ bz, const float* __restrict__ Wff,
    const float* __restrict__ bff, const float* __restrict__ g1,
    const float* __restrict__ be1, const float* __restrict__ g2,
    const float* __restrict__ be2, const float* __restrict__ Wp1,
    const float* __restrict__ bp1, const float* __restrict__ Wp2,
    const float* __restrict__ bp2, float* __restrict__ out) {
  __shared__ float shA[8][3][33];
  __shared__ float shB[8][3][33];
  const int tid = threadIdx.x;
  const int j = tid & 31;
  const int slot = tid >> 5;
  const int n = blockIdx.x * 8 + slot;
  const size_t off = (size_t)n * 32 + j;

  const float x0 = lf[off], x1 = af[off], x2 = vf[off];

  auto ln3 = [&](float a0, float a1, float a2, const float* g,
                 const float* be, float* o) {
    float s = a0 + a1 + a2;
    s += __shfl_xor(s, 1); s += __shfl_xor(s, 2); s += __shfl_xor(s, 4);
    s += __shfl_xor(s, 8); s += __shfl_xor(s, 16);
    const float mu = s * (1.0f / 96.0f);
    const float d0 = a0 - mu, d1 = a1 - mu, d2 = a2 - mu;
    float ss = d0 * d0 + d1 * d1 + d2 * d2;
    ss += __shfl_xor(ss, 1); ss += __shfl_xor(ss, 2); ss += __shfl_xor(ss, 4);
    ss += __shfl_xor(ss, 8); ss += __shfl_xor(ss, 16);
    const float rs = rsqrtf(ss * (1.0f / 96.0f) + 1e-5f);
    o[0] = d0 * rs * g[j] + be[j];
    o[1] = d1 * rs * g[32 + j] + be[32 + j];
    o[2] = d2 * rs * g[64 + j] + be[64 + j];
  };

  float z[3];
  ln3(x0, x1, x2, g1, be1, z);
  shA[slot][0][j] = z[0]; shA[slot][1][j] = z[1]; shA[slot][2][j] = z[2];
  __syncthreads();

  float qv[3], kv[3], vv[3];
  {
    const float bqj = bq[j], bkj = bk[j], bvj = bv[j];
    qv[0] = bqj; qv[1] = bqj; qv[2] = bqj;
    kv[0] = bkj; kv[1] = bkj; kv[2] = bkj;
    vv[0] = bvj; vv[1] = bvj; vv[2] = bvj;
    const float* wqr = Wq + j * 32;
    const float* wkr = Wk + j * 32;
    const float* wvr = Wv + j * 32;
#pragma unroll 8
    for (int k = 0; k < 32; ++k) {
      const float zz0 = shA[slot][0][k], zz1 = shA[slot][1][k],
                  zz2 = shA[slot][2][k];
      const float wq = wqr[k], wk_ = wkr[k], wv_ = wvr[k];
      qv[0] += wq * zz0;  qv[1] += wq * zz1;  qv[2] += wq * zz2;
      kv[0] += wk_ * zz0; kv[1] += wk_ * zz1; kv[2] += wk_ * zz2;
      vv[0] += wv_ * zz0; vv[1] += wv_ * zz1; vv[2] += wv_ * zz2;
    }
  }

  float at[3][3];
#pragma unroll
  for (int s = 0; s < 3; ++s)
#pragma unroll
    for (int t2 = 0; t2 < 3; ++t2) {
      float p = qv[s] * kv[t2];
      p += __shfl_xor(p, 1); p += __shfl_xor(p, 2); p += __shfl_xor(p, 4);
      at[s][t2] = p;
    }
#pragma unroll
  for (int s = 0; s < 3; ++s) {
    const float m = fmaxf(fmaxf(at[s][0], at[s][1]), at[s][2]);
    const float e0 = __expf(at[s][0] - m), e1 = __expf(at[s][1] - m),
                e2 = __expf(at[s][2] - m);
    const float sc = 0.35355339059327373f * __fdividef(1.0f, e0 + e1 + e2);
    at[s][0] = e0 * sc; at[s][1] = e1 * sc; at[s][2] = e2 * sc;
  }
  float zc[3];
#pragma unroll
  for (int s = 0; s < 3; ++s)
    zc[s] = at[s][0] * vv[0] + at[s][1] * vv[1] + at[s][2] * vv[2];
  shB[slot][0][j] = zc[0]; shB[slot][1][j] = zc[1]; shB[slot][2][j] = zc[2];
  __syncthreads();

  const float bzj = bz[j];
  float z2a[3] = {bzj + x0, bzj + x1, bzj + x2};
  {
    const float* wzr = Wz + j * 32;
#pragma unroll 8
    for (int k = 0; k < 32; ++k) {
      const float w = wzr[k];
      z2a[0] += w * shB[slot][0][k];
      z2a[1] += w * shB[slot][1][k];
      z2a[2] += w * shB[slot][2][k];
    }
  }

  float zn[3];
  ln3(z2a[0], z2a[1], z2a[2], g2, be2, zn);
  shA[slot][0][j] = zn[0]; shA[slot][1][j] = zn[1]; shA[slot][2][j] = zn[2];
  __syncthreads();

  const float bffj = bff[j];
  float Za[3] = {bffj + z2a[0], bffj + z2a[1], bffj + z2a[2]};
  {
    const float* wfr = Wff + j * 32;
#pragma unroll 8
    for (int k = 0; k < 32; ++k) {
      const float w = wfr[k];
      Za[0] += w * shA[slot][0][k];
      Za[1] += w * shA[slot][1][k];
      Za[2] += w * shA[slot][2][k];
    }
  }
  shB[slot][0][j] = Za[0]; shB[slot][1][j] = Za[1]; shB[slot][2][j] = Za[2];
  __syncthreads();

  float p = bp1[j];
  {
    const float* wpr = Wp1 + j * 96;
#pragma unroll
    for (int s = 0; s < 3; ++s)
#pragma unroll 8
      for (int k = 0; k < 32; ++k) p += wpr[s * 32 + k] * shB[slot][s][k];
  }
  p = fmaxf(p, 0.0f);
  float l0 = Wp2[j] * p, l1 = Wp2[32 + j] * p;
  l0 += __shfl_xor(l0, 1); l0 += __shfl_xor(l0, 2); l0 += __shfl_xor(l0, 4);
  l0 += __shfl_xor(l0, 8); l0 += __shfl_xor(l0, 16);
  l1 += __shfl_xor(l1, 1); l1 += __shfl_xor(l1, 2); l1 += __shfl_xor(l1, 4);
  l1 += __shfl_xor(l1, 8); l1 += __shfl_xor(l1, 16);
  l0 += bp2[0]; l1 += bp2[1];
  const float mx = fmaxf(l0, l1);
  const float e0 = __expf(l0 - mx), e1 = __expf(l1 - mx);
  const float inv = __fdividef(1.0f, e0 + e1);
  if (j == 0) {
    out[(size_t)n * 2 + 0] = e0 * inv;
    out[(size_t)n * 2 + 1] = e1 * inv;
  }
}

// ---------------------------------------------------------------------------
extern "C" void kernel_launch(void* const* d_in, const int* in_sizes, int n_in,
                              void* d_out, int out_size, void* d_ws,
                              size_t ws_size, hipStream_t stream) {
  const float* l    = (const float*)d_in[0];
  const float* a    = (const float*)d_in[1];
  const float* v    = (const float*)d_in[2];
  const float* lW1  = (const float*)d_in[3];
  const float* lb1  = (const float*)d_in[4];
  const float* lW2  = (const float*)d_in[5];
  const float* lb2  = (const float*)d_in[6];
  const float* aWih = (const float*)d_in[7];
  const float* aWhh = (const float*)d_in[8];
  const float* abih = (const float*)d_in[9];
  const float* abhh = (const float*)d_in[10];
  const float* aWo  = (const float*)d_in[11];
  const float* abo  = (const float*)d_in[12];
  const float* vWih = (const float*)d_in[13];
  const float* vWhh = (const float*)d_in[14];
  const float* vbih = (const float*)d_in[15];
  const float* vbhh = (const float*)d_in[16];
  const float* vWo  = (const float*)d_in[17];
  const float* vbo  = (const float*)d_in[18];
  const float* Wq   = (const float*)d_in[19];
  const float* bq   = (const float*)d_in[20];
  const float* Wk   = (const float*)d_in[21];
  const float* bk   = (const float*)d_in[22];
  const float* Wv   = (const float*)d_in[23];
  const float* bv   = (const float*)d_in[24];
  const float* Wz   = (const float*)d_in[25];
  const float* bz   = (const float*)d_in[26];
  const float* Wff  = (const float*)d_in[27];
  const float* bff  = (const float*)d_in[28];
  const float* g1   = (const float*)d_in[29];
  const float* be1  = (const float*)d_in[30];
  const float* g2   = (const float*)d_in[31];
  const float* be2  = (const float*)d_in[32];
  const float* Wp1  = (const float*)d_in[33];
  const float* bp1  = (const float*)d_in[34];
  const float* Wp2  = (const float*)d_in[35];
  const float* bp2  = (const float*)d_in[36];

  float* out = (float*)d_out;
  float* ws = (float*)d_ws;
  float* lfw = ws;
  float* afw = ws + 4096 * 32;
  float* vfw = ws + 2 * 4096 * 32;

  hipLaunchKernelGGL(lstm_both, dim3(512), dim3(256), 0, stream, a, v, aWih,
                     aWhh, abih, abhh, aWo, abo, vWih, vWhh, vbih, vbhh, vWo,
                     vbo, afw, vfw);
  hipLaunchKernelGGL(lf_kernel, dim3(256), dim3(256), 0, stream, l, lW1, lb1,
                     lW2, lb2, lfw);
  hipLaunchKernelGGL(head_kernel, dim3(512), dim3(256), 0, stream, lfw, afw,
                     vfw, Wq, bq, Wk, bk, Wv, bv, Wz, bz, Wff, bff, g1, be1,
                     g2, be2, Wp1, bp1, Wp2, bp2, out);
}